// Round 11
// baseline (224.817 us; speedup 1.0000x reference)
//
#include <hip/hip_runtime.h>
#include <hip/hip_bf16.h>

typedef float   f32x4   __attribute__((ext_vector_type(4)));
typedef __bf16  bf16x8  __attribute__((ext_vector_type(8)));
typedef unsigned short u16x8 __attribute__((ext_vector_type(8)));
typedef unsigned short u16x4 __attribute__((ext_vector_type(4)));

#define DEVI __device__ __forceinline__

DEVI unsigned short f2bf_bits(float f) {
    __bf16 h = (__bf16)f;
    return __builtin_bit_cast(unsigned short, h);
}

DEVI f32x4 mfma_bf16(bf16x8 a, bf16x8 b, f32x4 c) {
    return __builtin_amdgcn_mfma_f32_16x16x32_bf16(a, b, c, 0, 0, 0);
}

// Native v_exp_f32 (2^x); log2(e) pre-folded into Q-projection scale.
DEVI float fast_exp2(float x) {
#if __has_builtin(__builtin_amdgcn_exp2f)
    return __builtin_amdgcn_exp2f(x);
#else
    float r;
    asm("v_exp_f32 %0, %1" : "=v"(r) : "v"(x));
    return r;
#endif
}

// Async global->LDS, 16B per lane; swizzle via pre-permuted global source.
DEVI void gload16(const void* g, void* l) {
    __builtin_amdgcn_global_load_lds(
        (const __attribute__((address_space(1))) void*)g,
        (__attribute__((address_space(3))) void*)l, 16, 0, 0);
}

// ---------------------------------------------------------------------------
// W f32->bf16 pre-convert (Wq,Wk,Wv -> contiguous bf16).
// ---------------------------------------------------------------------------
__global__ __launch_bounds__(256) void convert_w_kernel(
    const float* __restrict__ Wq, const float* __restrict__ Wk,
    const float* __restrict__ Wv, unsigned short* __restrict__ Wb)
{
    int idx = blockIdx.x * 256 + threadIdx.x;
    int which = idx >> 17;
    int off = (idx & 131071) * 8;
    const float* src = which == 0 ? Wq : (which == 1 ? Wk : Wv);
    f32x4 a = *(const f32x4*)(src + off);
    f32x4 b = *(const f32x4*)(src + off + 4);
    u16x8 h;
#pragma unroll
    for (int j = 0; j < 4; ++j) { h[j] = f2bf_bits(a[j]); h[4 + j] = f2bf_bits(b[j]); }
    *(u16x8*)(Wb + (size_t)which * 1048576 + off) = h;
}

// ---------------------------------------------------------------------------
// GEMM: C[M,N] = A[M,K] @ W[N,K]^T + bias, scale on (val+bias).
// 128x128 tile, BK=64. bf16 operand: global_load_lds w/ pre-swizzled source.
// f32 operand: T14 async-split reg-staging (issue after barrier, write next
// iter). Unchanged from R10.
// ---------------------------------------------------------------------------
template <bool A_ASYNC, bool OUT_F32>
__global__ __launch_bounds__(256) void gemm_bt_kernel(
    const void* __restrict__ Ap, const void* __restrict__ Wp,
    const float* __restrict__ bias, void* __restrict__ Cp,
    int M, int N, int K, float scale)
{
    __shared__ __align__(16) char ldsA[128 * 128];
    __shared__ __align__(16) char ldsB[128 * 128];
    const int t = threadIdx.x;
    const int wave = t >> 6, lane = t & 63;
    const int g = lane >> 4, c = lane & 15;
    const int rowbase = blockIdx.x * 128;
    const int colbase = blockIdx.y * 128;
    const int wr = (wave >> 1) * 64, wc = (wave & 1) * 64;

    const int arow = lane >> 3;
    const int aslot = (lane & 7) ^ arow;

    const float* fbase[4];
#pragma unroll
    for (int ch = 0; ch < 4; ++ch) {
        int id = ch * 256 + t;
        int row = id >> 3;
        int col = (id & 7) * 8;
        if constexpr (A_ASYNC)
            fbase[ch] = (const float*)Wp + (size_t)(colbase + row) * K + col;
        else
            fbase[ch] = (const float*)Ap + (size_t)(rowbase + row) * K + col;
    }

    f32x4 pre0[4], pre1[4];
#pragma unroll
    for (int ch = 0; ch < 4; ++ch) {
        pre0[ch] = *(const f32x4*)(fbase[ch]);
        pre1[ch] = *(const f32x4*)(fbase[ch] + 4);
    }

    f32x4 acc[4][4] = {};

    for (int kt = 0; kt < K; kt += 64) {
        if constexpr (A_ASYNC) {
            const unsigned short* Ab = (const unsigned short*)Ap;
#pragma unroll
            for (int j = 0; j < 4; ++j) {
                int rg = wave * 4 + j;
                int row = rg * 8 + arow;
                gload16(Ab + (size_t)(rowbase + row) * K + kt + aslot * 8,
                        ldsA + rg * 1024);
            }
        } else {
            const unsigned short* Wb = (const unsigned short*)Wp;
#pragma unroll
            for (int j = 0; j < 4; ++j) {
                int rg = wave * 4 + j;
                int row = rg * 8 + arow;
                gload16(Wb + (size_t)(colbase + row) * K + kt + aslot * 8,
                        ldsB + rg * 1024);
            }
        }

#pragma unroll
        for (int ch = 0; ch < 4; ++ch) {
            int id = ch * 256 + t;
            int row = id >> 3;
            int col = (id & 7) * 8;
            int dst = row * 128 + ((col * 2) ^ ((row & 7) << 4));
            u16x8 hv;
#pragma unroll
            for (int j = 0; j < 4; ++j) { hv[j] = f2bf_bits(pre0[ch][j]); hv[4 + j] = f2bf_bits(pre1[ch][j]); }
            if constexpr (A_ASYNC)
                *(u16x8*)(ldsB + dst) = hv;
            else
                *(u16x8*)(ldsA + dst) = hv;
        }
        __syncthreads();

        if (kt + 64 < K) {
#pragma unroll
            for (int ch = 0; ch < 4; ++ch) {
                pre0[ch] = *(const f32x4*)(fbase[ch] + kt + 64);
                pre1[ch] = *(const f32x4*)(fbase[ch] + kt + 68);
            }
        }

#pragma unroll
        for (int kk = 0; kk < 2; ++kk) {
            bf16x8 af[4], bfr[4];
#pragma unroll
            for (int i = 0; i < 4; ++i) {
                int ra = wr + i * 16 + c;
                af[i] = *(const bf16x8*)(ldsA + ra * 128 + ((kk * 64 + g * 16) ^ ((ra & 7) << 4)));
                int rb = wc + i * 16 + c;
                bfr[i] = *(const bf16x8*)(ldsB + rb * 128 + ((kk * 64 + g * 16) ^ ((rb & 7) << 4)));
            }
#pragma unroll
            for (int i = 0; i < 4; ++i)
#pragma unroll
                for (int j = 0; j < 4; ++j)
                    acc[i][j] = mfma_bf16(af[i], bfr[j], acc[i][j]);
        }
        __syncthreads();
    }

#pragma unroll
    for (int j = 0; j < 4; ++j) {
        int coln = colbase + wc + j * 16 + c;
        float bv = bias[coln];
#pragma unroll
        for (int i = 0; i < 4; ++i) {
            int row0 = rowbase + wr + i * 16 + g * 4;
#pragma unroll
            for (int r = 0; r < 4; ++r) {
                float val = (acc[i][j][r] + bv) * scale;
                if constexpr (OUT_F32)
                    ((float*)Cp)[(size_t)(row0 + r) * N + coln] = val;
                else
                    ((unsigned short*)Cp)[(size_t)(row0 + r) * N + coln] = f2bf_bits(val);
            }
        }
    }
}

// ---------------------------------------------------------------------------
// Transpose Vp[B,S,D] (head-sliced) -> Vt[B,H,hd,S].
// ---------------------------------------------------------------------------
__global__ __launch_bounds__(256) void transpose_v_kernel(
    const unsigned short* __restrict__ Vp, unsigned short* __restrict__ Vt)
{
    __shared__ unsigned short tile[64][72];
    const int t = threadIdx.x;
    const int bh = blockIdx.y, b = bh >> 4, h = bh & 15;
    const int s0 = blockIdx.x * 64;
#pragma unroll
    for (int ch = 0; ch < 2; ++ch) {
        int id = ch * 256 + t;
        int srow = id >> 3, dcol = (id & 7) * 8;
        u16x8 v = *(const u16x8*)(Vp + (size_t)(b * 2048 + s0 + srow) * 1024 + h * 64 + dcol);
        *(u16x8*)&tile[srow][dcol] = v;
    }
    __syncthreads();
#pragma unroll
    for (int ch = 0; ch < 2; ++ch) {
        int id = ch * 256 + t;
        int drow = id >> 3, scol = (id & 7) * 8;
        u16x8 ov;
#pragma unroll
        for (int j = 0; j < 8; ++j) ov[j] = tile[scol + j][drow];
        *(u16x8*)(Vt + (size_t)(bh * 64 + drow) * 2048 + s0 + scol) = ov;
    }
}

// ---------------------------------------------------------------------------
// Flash attention. Grid (S/256, B*H) = 512 blocks = exactly 2/CU (no tail).
// 4 waves x 64 q-rows (4 q-sets of 16). R10 showed the kernel rides the LDS
// bandwidth roofline (model 7.3GB -> 101us; measured 99us). K/V staging and
// fragment reads are q-row-independent, so 4 q-sets halves their share again:
// per-128-row LDS bytes 112KB -> 72KB. Costs: LDS 48KB/block, VGPR ~200
// (s[4][4] live during softmax) — fine at the 2-waves/SIMD we need.
// P = fast_exp2(S) (native v_exp_f32). Fixed-max softmax; swapped QK^T;
// packed P writes; async-STAGE prefetch. No setprio (R6).
// ---------------------------------------------------------------------------
__global__ __launch_bounds__(256) void attn_kernel(
    const unsigned short* __restrict__ Qp, const unsigned short* __restrict__ Kp,
    const unsigned short* __restrict__ Vt, unsigned short* __restrict__ ctx)
{
    __shared__ __align__(16) char ldsK[64 * 128];
    __shared__ __align__(16) char ldsV[64 * 128];
    __shared__ __align__(16) char ldsP[4][4][16 * 128];  // wave, qset
    const int t = threadIdx.x;
    const int wave = t >> 6, lane = t & 63;
    const int g = lane >> 4, c = lane & 15;
    const int bh = blockIdx.y, b = bh >> 4, h = bh & 15;
    const int qb = blockIdx.x * 256;

    // Q A-frags for 4 q-sets: row = lane&15, k = 8*(lane>>4)+j
    bf16x8 qf[4][2];
#pragma unroll
    for (int qs = 0; qs < 4; ++qs) {
        const unsigned short* q0 = Qp + (size_t)(b * 2048 + qb + wave * 64 + qs * 16 + c) * 1024 + h * 64;
        qf[qs][0] = *(const bf16x8*)(q0 + 8 * g);
        qf[qs][1] = *(const bf16x8*)(q0 + 32 + 8 * g);
    }

    f32x4 o[4][4] = {};
    float psum[4] = {0.f, 0.f, 0.f, 0.f};

    const int row0 = t >> 3, colB = (t & 7) * 8;
    const int row1 = 32 + row0;
    const int dst0 = row0 * 128 + ((colB * 2) ^ ((row0 & 7) << 4));
    const int dst1 = row1 * 128 + ((colB * 2) ^ ((row1 & 7) << 4));
    const unsigned short* Ksrc = Kp + (size_t)(b * 2048) * 1024 + h * 64;
    const unsigned short* Vsrc = Vt + (size_t)(bh * 64) * 2048;

    u16x8 kv0 = *(const u16x8*)(Ksrc + (size_t)row0 * 1024 + colB);
    u16x8 kv1 = *(const u16x8*)(Ksrc + (size_t)row1 * 1024 + colB);
    u16x8 vv0 = *(const u16x8*)(Vsrc + (size_t)row0 * 2048 + colB);
    u16x8 vv1 = *(const u16x8*)(Vsrc + (size_t)row1 * 2048 + colB);

    for (int kb = 0; kb < 2048; kb += 64) {
        *(u16x8*)(ldsK + dst0) = kv0;
        *(u16x8*)(ldsK + dst1) = kv1;
        *(u16x8*)(ldsV + dst0) = vv0;
        *(u16x8*)(ldsV + dst1) = vv1;
        __syncthreads();

        if (kb + 64 < 2048) {
            kv0 = *(const u16x8*)(Ksrc + (size_t)(kb + 64 + row0) * 1024 + colB);
            kv1 = *(const u16x8*)(Ksrc + (size_t)(kb + 64 + row1) * 1024 + colB);
            vv0 = *(const u16x8*)(Vsrc + (size_t)row0 * 2048 + kb + 64 + colB);
            vv1 = *(const u16x8*)(Vsrc + (size_t)row1 * 2048 + kb + 64 + colB);
        }

        // S^T = K Q^T for 4 q-sets; K-frags read once, used 4x
        f32x4 s[4][4] = {};
#pragma unroll
        for (int kk = 0; kk < 2; ++kk) {
            bf16x8 kf[4];
#pragma unroll
            for (int ti = 0; ti < 4; ++ti) {
                int rk = ti * 16 + c;
                kf[ti] = *(const bf16x8*)(ldsK + rk * 128 + ((kk * 64 + g * 16) ^ ((rk & 7) << 4)));
            }
#pragma unroll
            for (int qs = 0; qs < 4; ++qs)
#pragma unroll
                for (int ti = 0; ti < 4; ++ti)
                    s[qs][ti] = mfma_bf16(kf[ti], qf[qs][kk], s[qs][ti]);
        }

        // P = exp2(S); lane-local psum; packed b64 writes into per-qset P
#pragma unroll
        for (int qs = 0; qs < 4; ++qs) {
            char* pw = ldsP[wave][qs];
#pragma unroll
            for (int ti = 0; ti < 4; ++ti) {
                float p0 = fast_exp2(s[qs][ti][0]);
                float p1 = fast_exp2(s[qs][ti][1]);
                float p2 = fast_exp2(s[qs][ti][2]);
                float p3 = fast_exp2(s[qs][ti][3]);
                psum[qs] += (p0 + p1) + (p2 + p3);
                u16x4 hp;
                hp[0] = f2bf_bits(p0); hp[1] = f2bf_bits(p1);
                hp[2] = f2bf_bits(p2); hp[3] = f2bf_bits(p3);
                *(u16x4*)(pw + c * 128 + ((ti * 32 + g * 8) ^ ((c & 7) << 4))) = hp;
            }
        }

        // O += P V ; V-frags read once, used by all 4 q-sets
#pragma unroll
        for (int kk = 0; kk < 2; ++kk) {
            bf16x8 vf[4];
#pragma unroll
            for (int ti = 0; ti < 4; ++ti) {
                int rv = ti * 16 + c;
                vf[ti] = *(const bf16x8*)(ldsV + rv * 128 + ((kk * 64 + g * 16) ^ ((rv & 7) << 4)));
            }
#pragma unroll
            for (int qs = 0; qs < 4; ++qs) {
                bf16x8 pa = *(const bf16x8*)(ldsP[wave][qs] + c * 128 + ((kk * 64 + g * 16) ^ ((c & 7) << 4)));
#pragma unroll
                for (int ti = 0; ti < 4; ++ti)
                    o[qs][ti] = mfma_bf16(pa, vf[ti], o[qs][ti]);
            }
        }
        __syncthreads();
    }

#pragma unroll
    for (int qs = 0; qs < 4; ++qs) {
        float ps = psum[qs];
        ps += __shfl_xor(ps, 16);
        ps += __shfl_xor(ps, 32);
#pragma unroll
        for (int r = 0; r < 4; ++r) {
            float inv = 1.0f / __shfl(ps, 4 * g + r);
            int row = qb + wave * 64 + qs * 16 + 4 * g + r;
#pragma unroll
            for (int ti = 0; ti < 4; ++ti) {
                int col = h * 64 + ti * 16 + c;
                ctx[(size_t)(b * 2048 + row) * 1024 + col] = f2bf_bits(o[qs][ti][r] * inv);
            }
        }
    }
}

// ---------------------------------------------------------------------------
extern "C" void kernel_launch(void* const* d_in, const int* in_sizes, int n_in,
                              void* d_out, int out_size, void* d_ws, size_t ws_size,
                              hipStream_t stream)
{
    const float* q  = (const float*)d_in[0];
    const float* k  = (const float*)d_in[1];
    const float* v  = (const float*)d_in[2];
    const float* Wq = (const float*)d_in[3];
    const float* bq = (const float*)d_in[4];
    const float* Wk = (const float*)d_in[5];
    const float* bk = (const float*)d_in[6];
    const float* Wv = (const float*)d_in[7];
    const float* bv = (const float*)d_in[8];
    const float* Wo = (const float*)d_in[9];
    const float* bo = (const float*)d_in[10];
    float* out = (float*)d_out;

    char* ws = (char*)d_ws;
    const size_t SZ = (size_t)8192 * 1024 * 2; // 16 MiB per bf16 [M,D] buffer
    unsigned short* Qp = (unsigned short*)(ws);
    unsigned short* Kp = (unsigned short*)(ws + SZ);
    unsigned short* Vp = (unsigned short*)(ws + 2 * SZ);
    unsigned short* Vt = (unsigned short*)(ws + 3 * SZ);
    unsigned short* ctx = Vp;  // Vp dead after transpose; reuse for ctx
    unsigned short* Wbf = Vt;  // W bf16 parked in Vt region (dead until transpose)

    const float QSCALE = 0.1803368801111244f; // 0.125 * log2(e) for exp2 attn

    convert_w_kernel<<<dim3(1536), 256, 0, stream>>>(Wq, Wk, Wv, Wbf);

    dim3 gg(64, 8);
    gemm_bt_kernel<false, false><<<gg, 256, 0, stream>>>(q, Wbf,           bq, Qp, 8192, 1024, 1024, QSCALE);
    gemm_bt_kernel<false, false><<<gg, 256, 0, stream>>>(k, Wbf + 1048576, bk, Kp, 8192, 1024, 1024, 1.0f);
    gemm_bt_kernel<false, false><<<gg, 256, 0, stream>>>(v, Wbf + 2097152, bv, Vp, 8192, 1024, 1024, 1.0f);
    transpose_v_kernel<<<dim3(32, 64), 256, 0, stream>>>(Vp, Vt);
    attn_kernel<<<dim3(8, 64), 256, 0, stream>>>(Qp, Kp, Vt, ctx);
    gemm_bt_kernel<true, true><<<gg, 256, 0, stream>>>(ctx, Wo, bo, out, 8192, 1024, 1024, 1.0f);
}